// Round 2
// 1543.375 us; speedup vs baseline: 3.1775x; 3.1775x over previous
//
#include <hip/hip_runtime.h>
#include <math.h>

#define S_LEN 2048
#define DMODEL 1024
#define NHEAD 16
#define DHEAD 64
#define LN_EPS 1e-5f

// ---------------------------------------------------------------------------
// Kernel 1: QKV projections.  C[4096,1024] = X @ W + b, scattered per-head.
// Q,K -> TRANSPOSED [bh][64][s] (for conflict-free float4 LDS staging in attn);
// V   -> natural    [bh][s][64] (PV tile wants V[j][d] row-major).
// grid (64,16,3), block 256. Tiles: BM=64, BN=64, BK=16, 4x4 per thread.
// ---------------------------------------------------------------------------
__global__ __launch_bounds__(256) void qkv_proj_kernel(
    const float* __restrict__ q, const float* __restrict__ k_in, const float* __restrict__ v,
    const float* __restrict__ Wq, const float* __restrict__ bq,
    const float* __restrict__ Wk, const float* __restrict__ bk,
    const float* __restrict__ Wv, const float* __restrict__ bv,
    float* __restrict__ Qt, float* __restrict__ Kt, float* __restrict__ Vh)
{
    __shared__ __align__(16) float Xs[16][68];   // [k][m]
    __shared__ __align__(16) float Ws[16][68];   // [k][n]
    const int t  = threadIdx.x;
    const int tx = t & 15, ty = t >> 4;
    const int m0 = blockIdx.x * 64, n0 = blockIdx.y * 64;
    const int z  = blockIdx.z;
    const float* X    = (z == 0) ? q  : (z == 1) ? k_in : v;
    const float* W    = (z == 0) ? Wq : (z == 1) ? Wk   : Wv;
    const float* bias = (z == 0) ? bq : (z == 1) ? bk   : bv;

    float c[4][4] = {};
    for (int kt = 0; kt < 64; ++kt) {
        const int k0 = kt * 16;
        __syncthreads();
        #pragma unroll
        for (int i = 0; i < 4; ++i) {
            int e = t + i * 256;                       // 1024 elems: m=e>>4, k=e&15
            Xs[e & 15][e >> 4] = X[(size_t)(m0 + (e >> 4)) * DMODEL + (k0 + (e & 15))];
        }
        #pragma unroll
        for (int i = 0; i < 4; ++i) {
            int e = t + i * 256;                       // 1024 elems: k=e>>6, n=e&63
            Ws[e >> 6][e & 63] = W[(size_t)(k0 + (e >> 6)) * DMODEL + (n0 + (e & 63))];
        }
        __syncthreads();
        #pragma unroll
        for (int p = 0; p < 16; ++p) {
            float4 x4 = *(const float4*)&Xs[p][ty * 4];
            float4 w4 = *(const float4*)&Ws[p][tx * 4];
            float xa[4] = {x4.x, x4.y, x4.z, x4.w};
            float wa[4] = {w4.x, w4.y, w4.z, w4.w};
            #pragma unroll
            for (int i = 0; i < 4; ++i)
                #pragma unroll
                for (int j = 0; j < 4; ++j)
                    c[i][j] += xa[i] * wa[j];
        }
    }
    const int h = n0 >> 6;                             // whole block is one head
    #pragma unroll
    for (int i = 0; i < 4; ++i) {
        int m = m0 + ty * 4 + i;
        int b = m >> 11, s = m & 2047;
        int bh = b * NHEAD + h;
        if (z == 2) {
            int d0 = tx * 4;
            float4 val;
            val.x = c[i][0] + bias[n0 + d0 + 0];
            val.y = c[i][1] + bias[n0 + d0 + 1];
            val.z = c[i][2] + bias[n0 + d0 + 2];
            val.w = c[i][3] + bias[n0 + d0 + 3];
            *(float4*)(Vh + ((size_t)bh * S_LEN + s) * DHEAD + d0) = val;
        } else {
            float* T = (z == 0) ? Qt : Kt;
            #pragma unroll
            for (int j = 0; j < 4; ++j) {
                int d = tx * 4 + j;                    // within-head d (n0 = h*64)
                T[((size_t)bh * DHEAD + d) * S_LEN + s] = c[i][j] + bias[n0 + d];
            }
        }
    }
}

// ---------------------------------------------------------------------------
// Kernel 2: attention as two register-tiled GEMMs + two-pass softmax.
// One block = one (bh, 64 query rows). 256 thr, 4x4 accumulator per thread.
// Pass 1: per 64-key tile, scores = Q K^T (Q panel resident in LDS, K tile
//   streamed); mask+scale; RAW scores written to attn region of d_out;
//   running row max m and rescaled sum l maintained via 16-lane shfl_xor.
// Pass 2: per tile, re-read raw scores (L2/HBM), p = exp(s-m)/l, write final
//   probs (required output), transpose P into LDS, PV GEMM from V[j][d] tile.
// LDS: 2 x 64x68 f32 = 34.8 KB -> 4 blocks/CU. Grid 32x32 = 1024 blocks
// = exactly 4/CU over 256 CUs.
// ---------------------------------------------------------------------------
__global__ __launch_bounds__(256) void attn_kernel(
    const float* __restrict__ Qt, const float* __restrict__ Kt, const float* __restrict__ Vh,
    const unsigned char* __restrict__ mask,
    float* __restrict__ attn_out,   // [BH][S][S] region of d_out
    float* __restrict__ Oh)         // [B*S][1024] head-concat attention output
{
    __shared__ __align__(16) float QP[64][68];  // Q panel (pass1) / P tile (pass2)
    __shared__ __align__(16) float KV[64][68];  // K tile (pass1) / V tile (pass2)
    const int t  = threadIdx.x;
    const int tx = t & 15, ty = t >> 4;
    const int q0 = blockIdx.x * 64;
    const int bh = blockIdx.y;
    const int b  = bh >> 4, h = bh & 15;

    // Q panel [d][q] from transposed layout — coalesced float4, no transpose.
    #pragma unroll
    for (int i = 0; i < 4; ++i) {
        int e = t + i * 256;
        int d = e >> 4, q4 = (e & 15) * 4;
        *(float4*)&QP[d][q4] = *(const float4*)(Qt + ((size_t)bh * DHEAD + d) * S_LEN + q0 + q4);
    }

    float m[4], l[4];
    #pragma unroll
    for (int i = 0; i < 4; ++i) { m[i] = -INFINITY; l[i] = 0.f; }

    float* arow = attn_out + (size_t)bh * S_LEN * S_LEN;

    // ---- Pass 1: scores + online max/sum ----
    for (int jt = 0; jt < 32; ++jt) {
        const int jb = jt * 64;
        __syncthreads();
        #pragma unroll
        for (int i = 0; i < 4; ++i) {                  // K tile [d][j]
            int e = t + i * 256;
            int d = e >> 4, j4 = (e & 15) * 4;
            *(float4*)&KV[d][j4] = *(const float4*)(Kt + ((size_t)bh * DHEAD + d) * S_LEN + jb + j4);
        }
        __syncthreads();
        float c[4][4] = {};
        #pragma unroll 16
        for (int p = 0; p < 64; ++p) {
            float4 a4 = *(const float4*)&QP[p][ty * 4];  // broadcast per row-group
            float4 b4 = *(const float4*)&KV[p][tx * 4];  // 2-way (free)
            float aa[4] = {a4.x, a4.y, a4.z, a4.w};
            float bb[4] = {b4.x, b4.y, b4.z, b4.w};
            #pragma unroll
            for (int i = 0; i < 4; ++i)
                #pragma unroll
                for (int jj = 0; jj < 4; ++jj)
                    c[i][jj] += aa[i] * bb[jj];
        }
        #pragma unroll
        for (int i = 0; i < 4; ++i) {
            int qrow = q0 + ty * 4 + i;
            const unsigned char* mp = mask + ((size_t)b * S_LEN + qrow) * S_LEN + jb + tx * 4;
            float4 sv;
            sv.x = mp[0] ? -INFINITY : c[i][0] * 0.125f;
            sv.y = mp[1] ? -INFINITY : c[i][1] * 0.125f;
            sv.z = mp[2] ? -INFINITY : c[i][2] * 0.125f;
            sv.w = mp[3] ? -INFINITY : c[i][3] * 0.125f;
            *(float4*)(arow + (size_t)qrow * S_LEN + jb + tx * 4) = sv;   // raw scores
            // tile max over the 64-wide row (16 tx lanes x 4 each)
            float tm = fmaxf(fmaxf(sv.x, sv.y), fmaxf(sv.z, sv.w));
            #pragma unroll
            for (int off = 8; off > 0; off >>= 1) tm = fmaxf(tm, __shfl_xor(tm, off));
            float mn = fmaxf(m[i], tm);
            float tl = __expf(sv.x - mn) + __expf(sv.y - mn)
                     + __expf(sv.z - mn) + __expf(sv.w - mn);
            #pragma unroll
            for (int off = 8; off > 0; off >>= 1) tl += __shfl_xor(tl, off);
            l[i] = l[i] * __expf(m[i] - mn) + tl;
            m[i] = mn;
        }
    }
    float invl[4];
    #pragma unroll
    for (int i = 0; i < 4; ++i) invl[i] = 1.0f / l[i];

    // ---- Pass 2: normalize probs (required output) + PV GEMM ----
    float o[4][4] = {};
    for (int jt = 0; jt < 32; ++jt) {
        const int jb = jt * 64;
        __syncthreads();                               // prev-tile readers done
        #pragma unroll
        for (int i = 0; i < 4; ++i) {                  // V tile [j][d]
            int e = t + i * 256;
            int j = e >> 4, d4 = (e & 15) * 4;
            *(float4*)&KV[j][d4] = *(const float4*)(Vh + ((size_t)bh * S_LEN + jb + j) * DHEAD + d4);
        }
        #pragma unroll
        for (int i = 0; i < 4; ++i) {
            int qrow = q0 + ty * 4 + i;
            float4 sv = *(const float4*)(arow + (size_t)qrow * S_LEN + jb + tx * 4);
            float4 pv;
            pv.x = __expf(sv.x - m[i]) * invl[i];
            pv.y = __expf(sv.y - m[i]) * invl[i];
            pv.z = __expf(sv.z - m[i]) * invl[i];
            pv.w = __expf(sv.w - m[i]) * invl[i];
            *(float4*)(arow + (size_t)qrow * S_LEN + jb + tx * 4) = pv;   // final probs
            QP[tx * 4 + 0][ty * 4 + i] = pv.x;         // P transposed [j][q]
            QP[tx * 4 + 1][ty * 4 + i] = pv.y;
            QP[tx * 4 + 2][ty * 4 + i] = pv.z;
            QP[tx * 4 + 3][ty * 4 + i] = pv.w;
        }
        __syncthreads();
        #pragma unroll 16
        for (int p = 0; p < 64; ++p) {
            float4 a4 = *(const float4*)&QP[p][ty * 4];
            float4 b4 = *(const float4*)&KV[p][tx * 4];
            float aa[4] = {a4.x, a4.y, a4.z, a4.w};
            float bb[4] = {b4.x, b4.y, b4.z, b4.w};
            #pragma unroll
            for (int i = 0; i < 4; ++i)
                #pragma unroll
                for (int jj = 0; jj < 4; ++jj)
                    o[i][jj] += aa[i] * bb[jj];
        }
    }
    #pragma unroll
    for (int i = 0; i < 4; ++i) {
        int qrow = q0 + ty * 4 + i;
        float4 ov;
        ov.x = o[i][0]; ov.y = o[i][1]; ov.z = o[i][2]; ov.w = o[i][3];
        *(float4*)(Oh + ((size_t)(b * S_LEN + qrow)) * DMODEL + h * DHEAD + tx * 4) = ov;
    }
}

// ---------------------------------------------------------------------------
// Kernel 3: output projection + bias + residual.  Y = Oh @ Wo + bo + q
// grid (64,16), block 256. Same tiling as kernel 1.
// ---------------------------------------------------------------------------
__global__ __launch_bounds__(256) void out_proj_kernel(
    const float* __restrict__ Xin, const float* __restrict__ Wo, const float* __restrict__ bo,
    const float* __restrict__ resid, float* __restrict__ Y)
{
    __shared__ __align__(16) float Xs[16][68];
    __shared__ __align__(16) float Ws[16][68];
    const int t  = threadIdx.x;
    const int tx = t & 15, ty = t >> 4;
    const int m0 = blockIdx.x * 64, n0 = blockIdx.y * 64;

    float c[4][4] = {};
    for (int kt = 0; kt < 64; ++kt) {
        const int k0 = kt * 16;
        __syncthreads();
        #pragma unroll
        for (int i = 0; i < 4; ++i) {
            int e = t + i * 256;
            Xs[e & 15][e >> 4] = Xin[(size_t)(m0 + (e >> 4)) * DMODEL + (k0 + (e & 15))];
        }
        #pragma unroll
        for (int i = 0; i < 4; ++i) {
            int e = t + i * 256;
            Ws[e >> 6][e & 63] = Wo[(size_t)(k0 + (e >> 6)) * DMODEL + (n0 + (e & 63))];
        }
        __syncthreads();
        #pragma unroll
        for (int p = 0; p < 16; ++p) {
            float4 x4 = *(const float4*)&Xs[p][ty * 4];
            float4 w4 = *(const float4*)&Ws[p][tx * 4];
            float xa[4] = {x4.x, x4.y, x4.z, x4.w};
            float wa[4] = {w4.x, w4.y, w4.z, w4.w};
            #pragma unroll
            for (int i = 0; i < 4; ++i)
                #pragma unroll
                for (int j = 0; j < 4; ++j)
                    c[i][j] += xa[i] * wa[j];
        }
    }
    #pragma unroll
    for (int i = 0; i < 4; ++i) {
        int m = m0 + ty * 4 + i;
        size_t base = (size_t)m * DMODEL + n0 + tx * 4;
        float4 r4 = *(const float4*)(resid + base);
        float4 val;
        val.x = c[i][0] + bo[n0 + tx*4 + 0] + r4.x;
        val.y = c[i][1] + bo[n0 + tx*4 + 1] + r4.y;
        val.z = c[i][2] + bo[n0 + tx*4 + 2] + r4.z;
        val.w = c[i][3] + bo[n0 + tx*4 + 3] + r4.w;
        *(float4*)(Y + base) = val;
    }
}

// ---------------------------------------------------------------------------
// Kernel 4: LayerNorm per row (biased variance, eps inside rsqrt).
// grid 4096, block 256; each thread owns one float4 of the row.
// ---------------------------------------------------------------------------
__global__ __launch_bounds__(256) void ln_kernel(
    const float* __restrict__ Y, const float* __restrict__ gamma,
    const float* __restrict__ beta, float* __restrict__ out)
{
    const int row  = blockIdx.x;
    const int t    = threadIdx.x;
    const int lane = t & 63, wv = t >> 6;
    float4 x = ((const float4*)(Y + (size_t)row * DMODEL))[t];
    float s  = x.x + x.y + x.z + x.w;
    float sq = x.x*x.x + x.y*x.y + x.z*x.z + x.w*x.w;
    #pragma unroll
    for (int off = 32; off > 0; off >>= 1) {
        s  += __shfl_xor(s, off);
        sq += __shfl_xor(sq, off);
    }
    __shared__ float rs[4], rq[4];
    if (lane == 0) { rs[wv] = s; rq[wv] = sq; }
    __syncthreads();
    float S = rs[0] + rs[1] + rs[2] + rs[3];
    float Q = rq[0] + rq[1] + rq[2] + rq[3];
    float mu   = S * (1.0f / DMODEL);
    float var  = Q * (1.0f / DMODEL) - mu * mu;
    float rstd = rsqrtf(var + LN_EPS);
    float4 g  = ((const float4*)gamma)[t];
    float4 be = ((const float4*)beta)[t];
    float4 o;
    o.x = (x.x - mu) * rstd * g.x + be.x;
    o.y = (x.y - mu) * rstd * g.y + be.y;
    o.z = (x.z - mu) * rstd * g.z + be.z;
    o.w = (x.w - mu) * rstd * g.w + be.w;
    ((float4*)(out + (size_t)row * DMODEL))[t] = o;
}

// ---------------------------------------------------------------------------
extern "C" void kernel_launch(void* const* d_in, const int* in_sizes, int n_in,
                              void* d_out, int out_size, void* d_ws, size_t ws_size,
                              hipStream_t stream)
{
    const float* q    = (const float*)d_in[0];
    const float* k    = (const float*)d_in[1];
    const float* v    = (const float*)d_in[2];
    const unsigned char* mask = (const unsigned char*)d_in[3];
    const float* Wq   = (const float*)d_in[4];
    const float* bq   = (const float*)d_in[5];
    const float* Wk   = (const float*)d_in[6];
    const float* bk   = (const float*)d_in[7];
    const float* Wv   = (const float*)d_in[8];
    const float* bv   = (const float*)d_in[9];
    const float* Wo   = (const float*)d_in[10];
    const float* bo   = (const float*)d_in[11];
    const float* lng  = (const float*)d_in[12];
    const float* lnb  = (const float*)d_in[13];

    const size_t NTOK = (size_t)2 * S_LEN;           // 4096 rows
    const size_t HSZ  = NTOK * DMODEL;               // 4,194,304 floats per buffer
    float* ws   = (float*)d_ws;
    float* Qt   = ws;                                // [bh][64][s]  (transposed)
    float* Kt   = ws + HSZ;                          // [bh][64][s]  (transposed)
    float* Vh   = ws + 2 * HSZ;                      // [bh][s][64]
    float* Oh   = ws + 3 * HSZ;                      // [b*s][1024]
    float* Ytmp = ws;                                // reuse Qt region after attn

    float* out0 = (float*)d_out;                     // [B,S,1024]
    float* attn = out0 + HSZ;                        // [B,H,S,S]

    qkv_proj_kernel<<<dim3(64, 16, 3), 256, 0, stream>>>(q, k, v, Wq, bq, Wk, bk, Wv, bv,
                                                         Qt, Kt, Vh);
    attn_kernel<<<dim3(S_LEN / 64, 32), 256, 0, stream>>>(Qt, Kt, Vh, mask, attn, Oh);
    out_proj_kernel<<<dim3(64, 16), 256, 0, stream>>>(Oh, Wo, bo, q, Ytmp);
    ln_kernel<<<dim3(4096), 256, 0, stream>>>(Ytmp, lng, lnb, out0);
}